// Round 5
// baseline (4098.103 us; speedup 1.0000x reference)
//
#include <hip/hip_runtime.h>
#include <hip/hip_bf16.h>
#include <math.h>

#define L_LAYERS 4
#define BSZ 64
#define NTOK 196
#define CDIM 768
#define CNDIM 960
#define HIDDIM 3072
#define NHEAD 12
#define HD 64
#define HDK 80
#define MRED 49
#define ROWS (BSZ*NTOK)    /* 12544 */
#define RROWS (BSZ*MRED)   /* 3136 */
#define KVN 1728           /* 960 + 768 fused k|v output cols */

typedef __bf16 bf16x8 __attribute__((ext_vector_type(8)));
typedef float f32x4 __attribute__((ext_vector_type(4)));
typedef unsigned short u16x4 __attribute__((ext_vector_type(4)));

static __device__ inline float bf2f(unsigned short u) {
    unsigned int x = ((unsigned int)u) << 16;
    return __builtin_bit_cast(float, x);
}
static __device__ inline unsigned short f2bf(float f) {
    return __builtin_bit_cast(unsigned short, __float2bfloat16(f));
}
static __device__ inline unsigned int pack2bf(float lo, float hi) {
    return (unsigned int)f2bf(lo) | ((unsigned int)f2bf(hi) << 16);
}
// tanh-form GELU: x*sigmoid(1.5958x + 0.07135x^3); |err vs exact| ~3e-4
static __device__ inline float gelu_f(float x) {
    float t = x * (1.5957691216f + 0.0713548162f * x * x);
    return x * __builtin_amdgcn_rcpf(1.0f + __expf(-t));
}

// async 16B global -> LDS (wave-uniform LDS base + lane*16)
#define GLLDS16(gsrc, ldst)                                                        \
    __builtin_amdgcn_global_load_lds(                                              \
        (const __attribute__((address_space(1))) unsigned int*)(const void*)(gsrc),\
        (__attribute__((address_space(3))) unsigned int*)(void*)(ldst), 16, 0, 0)

// ---------------------------------------------------------------------------
// Weight prep: src fp32 (K x N) row-major -> dst bf16 (N x K) row-major.
// ---------------------------------------------------------------------------
__global__ void transpose_bf16_kernel(const float* __restrict__ src,
                                      unsigned short* __restrict__ dst,
                                      int K, int N, size_t srcLS, size_t dstLS) {
    __shared__ float tile[32][33];
    const float* s = src + (size_t)blockIdx.z * srcLS;
    unsigned short* d = dst + (size_t)blockIdx.z * dstLS;
    int k0 = blockIdx.y * 32, n0 = blockIdx.x * 32;
#pragma unroll
    for (int i = 0; i < 4; i++) {
        int k = k0 + threadIdx.y + i * 8, n = n0 + threadIdx.x;
        if (k < K && n < N) tile[threadIdx.y + i * 8][threadIdx.x] = s[(size_t)k * N + n];
    }
    __syncthreads();
#pragma unroll
    for (int i = 0; i < 4; i++) {
        int n = n0 + threadIdx.y + i * 8, k = k0 + threadIdx.x;
        if (n < N && k < K) d[(size_t)n * K + k] = f2bf(tile[threadIdx.x][threadIdx.y + i * 8]);
    }
}

// ---------------------------------------------------------------------------
// LayerNorm (one wave per row), optional GELU, bf16 output.
// ---------------------------------------------------------------------------
__global__ void ln_kernel(const float* __restrict__ x, const float* __restrict__ g,
                          const float* __restrict__ b, unsigned short* __restrict__ y,
                          int M, int C, float eps, int do_gelu) {
    int row = blockIdx.x * 4 + (threadIdx.x >> 6);
    int lane = threadIdx.x & 63;
    if (row >= M) return;
    const float* xr = x + (size_t)row * C;
    float s = 0.f, ss = 0.f;
    for (int c = lane; c < C; c += 64) { float v = xr[c]; s += v; ss += v * v; }
#pragma unroll
    for (int off = 32; off; off >>= 1) { s += __shfl_down(s, off); ss += __shfl_down(ss, off); }
    s = __shfl(s, 0); ss = __shfl(ss, 0);
    float mean = s / (float)C;
    float var = ss / (float)C - mean * mean;
    float rstd = rsqrtf(var + eps);
    unsigned short* yr = y + (size_t)row * C;
    for (int c = lane; c < C; c += 64) {
        float v = (xr[c] - mean) * rstd * g[c] + b[c];
        if (do_gelu) v = gelu_f(v);
        yr[c] = f2bf(v);
    }
}

// ---------------------------------------------------------------------------
// Depthwise 2x2 stride-2 conv on the token grid (14x14 -> 7x7), bf16 in/out.
// ---------------------------------------------------------------------------
__global__ void dwconv_kernel(const unsigned short* __restrict__ y,
                              const float* __restrict__ w,
                              const float* __restrict__ bias,
                              unsigned short* __restrict__ r0) {
    int bm = blockIdx.x;
    int b = bm / MRED, m = bm % MRED;
    int i = m / 7, j = m % 7;
    int r00 = b * NTOK + (2 * i) * 14 + 2 * j;
    for (int c = threadIdx.x; c < CDIM; c += 256) {
        float acc = bias[c];
        acc += bf2f(y[(size_t)(r00)      * CDIM + c]) * w[c * 4 + 0];
        acc += bf2f(y[(size_t)(r00 + 1)  * CDIM + c]) * w[c * 4 + 1];
        acc += bf2f(y[(size_t)(r00 + 14) * CDIM + c]) * w[c * 4 + 2];
        acc += bf2f(y[(size_t)(r00 + 15) * CDIM + c]) * w[c * 4 + 3];
        r0[(size_t)bm * CDIM + c] = f2bf(acc);
    }
}

// ---------------------------------------------------------------------------
// MFMA GEMM: 128 x BN tile (BN = 256 or 128), BK=32, 8 waves (2M x 4N),
// per-wave 64 x BN/4 output (acc <= 64 VGPRs) -> TWO blocks/CU (16 waves).
// Ring-3 LDS (3 slots of 24KB/16KB = 72/48 KB), prefetch distance 2:
// iter t computes slot t%3 while t+1 (landed) and t+2 (in flight) occupy the
// others. End-of-iter wait is counted `s_waitcnt vmcnt(LPS)` (LPS = loads per
// stage: 3 for BN=256, 2 for BN=128) -- never drains to 0 until the tail.
// Race-free: stage(t+2) writes slot (t-1)%3 whose readers (iter t-1) are
// lgkm-complete before the end-of-(t-1) barrier, which precedes the issue.
// Split-K (SK>1, MODE 2 only): grid = NR*NC*SK, block ks covers K/SK; the
// epilogue becomes f32 atomicAdd (residual already in outF; bias added by
// the ks==0 block only). Order-independent.
// T2 chunk swizzle via inverse-swizzled global source (rule #21).
// MODE 0: bf16 = acc ; 1: fp32 = acc+bias ; 2: fp32 += acc+bias ;
// 3: bf16 = gelu(acc+bias).  Epilogue masks gr<M, gc<N (padded tiles).
// ---------------------------------------------------------------------------
template <int MODE, int BN, int SK>
__global__ __launch_bounds__(512, 4) void gemm128_kernel(
    const unsigned short* __restrict__ A,
    const unsigned short* __restrict__ Bt,
    const float* __restrict__ bias,
    float* __restrict__ outF,
    unsigned short* __restrict__ outB,
    int M, int N, int K, int NR, int NC) {
    constexpr int NFR = BN / 64;            // B-frags per wave (4 or 2)
    constexpr int SLOT = 8192 + BN * 64;    // A 8KB + B BN*64B
    constexpr int LPS = (BN == 256) ? 3 : 2; // gllds per stage
    extern __shared__ __align__(16) char sb[];

    // split-K index (slowest), then XCD-aware tile swizzle within a split
    int id = blockIdx.x;
    int per = NR * NC;
    int ks = 0;
    if constexpr (SK > 1) { ks = id / per; id -= ks * per; }
    int gsize = 8 * NC;
    int g = id / gsize;
    int local = id - g * gsize;
    int rbase = g * 8;
    int Gg = NR - rbase; if (Gg > 8) Gg = 8;
    int col = local / Gg;
    int row = rbase + (local - col * Gg);
    int m0 = row * 128, n0 = col * BN;
    int KS = K / SK;                 // K-chunk per split (multiple of 32)
    int k0 = ks * KS;

    int tid = threadIdx.x;
    int w = tid >> 6, lane = tid & 63, quad = lane >> 4, l16 = lane & 15;
    int wm = w >> 2, wn = w & 3;        // 2 x 4 wave grid

    // ---- staging sources (inverse-swizzled 16B chunk within each 64B row) ----
    int sr = tid >> 2;                               // row 0..127
    int qs = ((tid & 3) - ((sr >> 1) & 3)) & 3;
    const unsigned short* aS0 = A  + (size_t)(m0 + sr) * K + k0 + qs * 8;
    const unsigned short* bS0 = Bt + (size_t)(n0 + sr) * K + k0 + qs * 8;
    const unsigned short* bS1 = Bt + (size_t)(n0 + sr + 128) * K + k0 + qs * 8;  // BN==256

    // ---- read-side fragment byte offsets (swizzled) ----
    int sq16 = ((quad + (l16 >> 1)) & 3) * 16;
    int aOff = (wm * 64 + l16) * 64 + sq16;                 // + mi*1024 + slot
    int bOff = 8192 + (wn * (BN / 4) + l16) * 64 + sq16;    // + ni*1024 + slot

    f32x4 zero4 = {0.f, 0.f, 0.f, 0.f};
    f32x4 acc[4][NFR];
#pragma unroll
    for (int mi = 0; mi < 4; mi++)
#pragma unroll
        for (int ni = 0; ni < NFR; ni++) acc[mi][ni] = zero4;

    int NT = KS >> 5;

#define STAGE3(slotptr, tt)                                                \
    do {                                                                   \
        int koff_ = (tt) * 32;                                             \
        GLLDS16(aS0 + koff_, (slotptr) + w * 1024);                        \
        GLLDS16(bS0 + koff_, (slotptr) + 8192 + w * 1024);                 \
        if constexpr (BN == 256) GLLDS16(bS1 + koff_, (slotptr) + 16384 + w * 1024); \
    } while (0)

    // prologue: stage tiles 0 and 1; wait tile 0 (tile 1 stays in flight)
    STAGE3(sb, 0);
    if (NT > 1) {
        STAGE3(sb + SLOT, 1);
        if constexpr (BN == 256) asm volatile("s_waitcnt vmcnt(3)" ::: "memory");
        else                     asm volatile("s_waitcnt vmcnt(2)" ::: "memory");
    } else {
        asm volatile("s_waitcnt vmcnt(0)" ::: "memory");
    }
    __builtin_amdgcn_s_barrier();

    int sC = 0;
    for (int t = 0; t < NT; ++t) {
        char* sc = sb + (size_t)sC * SLOT;
        if (t + 2 < NT) {
            int sP = sC + 2; if (sP >= 3) sP -= 3;
            STAGE3(sb + (size_t)sP * SLOT, t + 2);
        }
        bf16x8 af[4], bfr[NFR];
#pragma unroll
        for (int mi = 0; mi < 4; mi++)
            af[mi] = *(const bf16x8*)(sc + aOff + mi * 1024);
#pragma unroll
        for (int ni = 0; ni < NFR; ni++)
            bfr[ni] = *(const bf16x8*)(sc + bOff + ni * 1024);
        __builtin_amdgcn_s_setprio(1);
#pragma unroll
        for (int mi = 0; mi < 4; mi++)
#pragma unroll
            for (int ni = 0; ni < NFR; ni++)
                acc[mi][ni] = __builtin_amdgcn_mfma_f32_16x16x32_bf16(
                    af[mi], bfr[ni], acc[mi][ni], 0, 0, 0);
        __builtin_amdgcn_s_setprio(0);
        if (t + 2 < NT) {   // t+1 landed; t+2 (LPS loads) stays in flight
            if constexpr (BN == 256) asm volatile("s_waitcnt vmcnt(3)" ::: "memory");
            else                     asm volatile("s_waitcnt vmcnt(2)" ::: "memory");
        } else {
            asm volatile("s_waitcnt vmcnt(0)" ::: "memory");
        }
        __builtin_amdgcn_s_barrier();
        sC++; if (sC == 3) sC = 0;
    }
#undef STAGE3

    // --- epilogue: repack each wave's 16 x (BN/4) slices through private LDS ---
    __syncthreads();
    float* eld = (float*)(sb + w * (BN == 256 ? 4096 : 2048));
    int colbase = n0 + wn * (BN / 4);
#pragma unroll
    for (int mi = 0; mi < 4; mi++) {
#pragma unroll
        for (int ni = 0; ni < NFR; ni++)
#pragma unroll
            for (int rr = 0; rr < 4; rr++)
                eld[(quad * 4 + rr) * (BN / 4) + ni * 16 + l16] = acc[mi][ni][rr];
        int rowb = m0 + wm * 64 + mi * 16;
        constexpr int NP = (BN == 256) ? 4 : 2;
#pragma unroll
        for (int p = 0; p < NP; p++) {
            int r, c;
            if constexpr (BN == 256) { r = p * 4 + quad;        c = l16 * 4; }
            else                     { r = p * 8 + (lane >> 3); c = (lane & 7) * 4; }
            int gr = rowb + r, gc = colbase + c;
            if (gr < M && gc < N) {
                f32x4 v4 = *(f32x4*)(eld + r * (BN / 4) + c);
                if (MODE == 0) {
                    u16x4 h;
#pragma unroll
                    for (int e = 0; e < 4; e++) h[e] = f2bf(v4[e]);
                    *(u16x4*)(outB + (size_t)gr * N + gc) = h;
                } else {
                    f32x4 b4 = *(const f32x4*)(bias + gc);
                    if (MODE == 1) {
                        *(f32x4*)(outF + (size_t)gr * N + gc) = v4 + b4;
                    } else if (MODE == 2) {
                        if constexpr (SK == 1) {
                            f32x4 o4 = *(f32x4*)(outF + (size_t)gr * N + gc);
                            *(f32x4*)(outF + (size_t)gr * N + gc) = o4 + v4 + b4;
                        } else {
                            f32x4 v = v4;
                            if (ks == 0) v = v + b4;
                            float* dp = outF + (size_t)gr * N + gc;
                            atomicAdd(dp + 0, v[0]);
                            atomicAdd(dp + 1, v[1]);
                            atomicAdd(dp + 2, v[2]);
                            atomicAdd(dp + 3, v[3]);
                        }
                    } else {  // MODE 3
                        u16x4 h;
#pragma unroll
                        for (int e = 0; e < 4; e++) h[e] = f2bf(gelu_f(v4[e] + b4[e]));
                        *(u16x4*)(outB + (size_t)gr * N + gc) = h;
                    }
                }
            }
        }
    }
}

// ---------------------------------------------------------------------------
// MFMA attention. One block per (b,h), 8 waves. Swapped-operand QK^T:
// S^T = mfma(A=K_frag, B=Q_frag) so the k-reduction is in-lane + 2 shfl_xor.
// V staged in LDS pre-permuted to the PV B-operand k-order, so the C-layout
// P^T fragments feed PV mfma directly (no cross-lane shuffles):
//   V2[d][c], c = 32s + 8q + j  ->  ktilde = 32s + 16*(j>=4) + 4q + (j&3)
// K_lds[64][96] (d-pad zeroed); O^T bounced via per-wave LDS tile (stride 72)
// to coalesced 16B stores. k>=49 masked at softmax; V2 pad rows zero.
// ---------------------------------------------------------------------------
__global__ __launch_bounds__(512, 4) void attn_kernel(
    const unsigned short* __restrict__ qb,   // (ROWS, CNDIM)
    const unsigned short* __restrict__ kv,   // (RROWS, KVN)
    unsigned short* __restrict__ ob) {       // (ROWS, CDIM)
    __shared__ __align__(16) unsigned short Ks[64 * 96];    // 12288 B
    __shared__ __align__(16) unsigned short V2[64 * 136];   // 17408 B (136 pad, cols 0..127 used)
    __shared__ __align__(16) unsigned short Os[8 * 16 * 72]; // 18432 B per-wave bounce

    int bh = blockIdx.x;
    int b = bh / NHEAD, h = bh % NHEAD;
    int tid = threadIdx.x;

    // --- zero K d-pad (cols 80..95, rows 0..48); disjoint from staged region ---
    for (int idx = tid; idx < 49 * 8; idx += 512) {
        int m = idx >> 3, c = idx & 7;
        ((unsigned int*)Ks)[m * 48 + 40 + c] = 0u;
    }
    // --- stage K rows: K_lds[m][d] = kv[b*49+m][h*80+d], 16B chunks ---
    for (int idx = tid; idx < 49 * 10; idx += 512) {
        int m = idx / 10, c = idx % 10;
        bf16x8 v = *(const bf16x8*)(kv + (size_t)(b * MRED + m) * KVN + h * HDK + c * 8);
        *(bf16x8*)(Ks + m * 96 + c * 8) = v;
    }
    // --- stage V pre-permuted: V2[d][c] = V[ktilde(c)][d] or 0 ---
    for (int idx = tid; idx < 64 * 128; idx += 512) {
        int d = idx >> 7, c = idx & 127;
        int s = c >> 5, q = (c >> 3) & 3, j = c & 7;
        int kt = s * 32 + ((j >> 2) << 4) + q * 4 + (j & 3);
        unsigned short val = 0;
        if (kt < MRED) val = kv[(size_t)(b * MRED + kt) * KVN + 960 + h * HD + d];
        V2[d * 136 + c] = val;
    }
    __syncthreads();

    int wv = tid >> 6, lane = tid & 63, quad = lane >> 4, l16 = lane & 15;
    unsigned short* Ow = Os + wv * 16 * 72;
    const float scale = 0.11180339887498949f;  // 1/sqrt(80)
    f32x4 zero4 = {0.f, 0.f, 0.f, 0.f};

#pragma unroll
    for (int gi = 0; gi < 2; ++gi) {
        int qg = wv + gi * 8;
        if (qg >= 13) break;
        // Q B-fragments (global, L2/L3-resident): B[d][q], d = quad*8+j
        const unsigned short* qrow =
            qb + (size_t)(b * NTOK + qg * 16 + l16) * CNDIM + h * HDK + quad * 8;
        bf16x8 bq0 = *(const bf16x8*)(qrow);
        bf16x8 bq1 = *(const bf16x8*)(qrow + 32);
        bf16x8 bq2 = *(const bf16x8*)(qrow + 64);

        // S^T = K @ Q^T : 4 k-frags x 3 K32-steps
        f32x4 sf[4];
#pragma unroll
        for (int kf = 0; kf < 4; kf++) sf[kf] = zero4;
#pragma unroll
        for (int kf = 0; kf < 4; kf++) {
            const unsigned short* kr = Ks + (kf * 16 + l16) * 96 + quad * 8;
            sf[kf] = __builtin_amdgcn_mfma_f32_16x16x32_bf16(
                *(const bf16x8*)(kr), bq0, sf[kf], 0, 0, 0);
            sf[kf] = __builtin_amdgcn_mfma_f32_16x16x32_bf16(
                *(const bf16x8*)(kr + 32), bq1, sf[kf], 0, 0, 0);
            sf[kf] = __builtin_amdgcn_mfma_f32_16x16x32_bf16(
                *(const bf16x8*)(kr + 64), bq2, sf[kf], 0, 0, 0);
        }

        // softmax over k (rows of S^T): lane holds k = 16kf + 4quad + r, col q=l16
        float p[4][4];
        float mx = -1e30f;
#pragma unroll
        for (int kf = 0; kf < 4; kf++)
#pragma unroll
            for (int r = 0; r < 4; r++) {
                float v = sf[kf][r] * scale;
                if (kf == 3) {
                    // k = 48 + 4*quad + r valid only for quad==0 && r==0
                    v = (r == 0 && quad == 0) ? v : -1e30f;
                }
                p[kf][r] = v;
                mx = fmaxf(mx, v);
            }
        mx = fmaxf(mx, __shfl_xor(mx, 16));
        mx = fmaxf(mx, __shfl_xor(mx, 32));
        float sum = 0.f;
#pragma unroll
        for (int kf = 0; kf < 4; kf++)
#pragma unroll
            for (int r = 0; r < 4; r++) {
                float e = __expf(p[kf][r] - mx);
                p[kf][r] = e;
                sum += e;
            }
        sum += __shfl_xor(sum, 16);
        sum += __shfl_xor(sum, 32);
        float inv = 1.0f / sum;
#pragma unroll
        for (int kf = 0; kf < 4; kf++)
#pragma unroll
            for (int r = 0; r < 4; r++) p[kf][r] *= inv;

        // pack P^T to bf16 pairs (r0,r1),(r2,r3) per frag
        unsigned int W[4][2];
#pragma unroll
        for (int kf = 0; kf < 4; kf++) {
            W[kf][0] = pack2bf(p[kf][0], p[kf][1]);
            W[kf][1] = pack2bf(p[kf][2], p[kf][3]);
        }

        // PV: O^T = V2 @ P : 4 d-frags x 2 K32-steps (V2 pre-permuted)
        f32x4 oacc[4];
#pragma unroll
        for (int df = 0; df < 4; df++) oacc[df] = zero4;
#pragma unroll
        for (int s = 0; s < 2; s++) {
            union { unsigned int u[4]; bf16x8 v; } bb;
            bb.u[0] = W[2 * s][0];
            bb.u[1] = W[2 * s][1];
            bb.u[2] = W[2 * s + 1][0];
            bb.u[3] = W[2 * s + 1][1];
#pragma unroll
            for (int df = 0; df < 4; df++) {
                const unsigned short* vr = V2 + (df * 16 + l16) * 136 + s * 32 + quad * 8;
                oacc[df] = __builtin_amdgcn_mfma_f32_16x16x32_bf16(
                    *(const bf16x8*)(vr), bb.v, oacc[df], 0, 0, 0);
            }
        }

        // O^T frags (row d = 16df+4quad+r, col q = l16) -> per-wave LDS bounce
#pragma unroll
        for (int df = 0; df < 4; df++) {
#pragma unroll
            for (int wp = 0; wp < 2; wp++) {
                unsigned int pk = pack2bf(oacc[df][2 * wp], oacc[df][2 * wp + 1]);
                *(unsigned int*)(Ow + l16 * 72 + df * 16 + quad * 4 + 2 * wp) = pk;
            }
        }
        // readback (same wave; compiler inserts lgkm wait) -> coalesced stores
        int q = lane >> 2, cch = lane & 3;
        int grow = qg * 16 + q;
        if (grow < NTOK) {
            unsigned short* dst = ob + (size_t)(b * NTOK + grow) * CDIM + h * HD + cch * 8;
            bf16x8 v0 = *(const bf16x8*)(Ow + q * 72 + cch * 8);
            bf16x8 v1 = *(const bf16x8*)(Ow + q * 72 + cch * 8 + 32);
            *(bf16x8*)(dst) = v0;
            *(bf16x8*)(dst + 32) = v1;
        }
    }
}

// ---------------------------------------------------------------------------

extern "C" void kernel_launch(void* const* d_in, const int* in_sizes, int n_in,
                              void* d_out, int out_size, void* d_ws, size_t ws_size,
                              hipStream_t stream) {
    (void)in_sizes; (void)n_in; (void)out_size; (void)ws_size;
    const float* x_in   = (const float*)d_in[0];
    const float* q_w    = (const float*)d_in[1];
    const float* dw_w   = (const float*)d_in[2];
    const float* dw_b   = (const float*)d_in[3];
    const float* pw_w   = (const float*)d_in[4];
    const float* pw_b   = (const float*)d_in[5];
    const float* lnr_g  = (const float*)d_in[6];
    const float* lnr_b  = (const float*)d_in[7];
    const float* k_w    = (const float*)d_in[8];
    const float* v_w    = (const float*)d_in[9];
    const float* proj_w = (const float*)d_in[10];
    const float* proj_b = (const float*)d_in[11];
    const float* ln1_g  = (const float*)d_in[12];
    const float* ln1_b  = (const float*)d_in[13];
    const float* ln2_g  = (const float*)d_in[14];
    const float* ln2_b  = (const float*)d_in[15];
    const float* fc1_w  = (const float*)d_in[16];
    const float* fc1_b  = (const float*)d_in[17];
    const float* fc2_w  = (const float*)d_in[18];
    const float* fc2_b  = (const float*)d_in[19];
    float* xout = (float*)d_out;
    char* ws = (char*)d_ws;

    // dynamic-LDS opt-in (>64KB) for the BN=256 ring-3 variants
    static bool attr_done = false;
    if (!attr_done) {
        hipFuncSetAttribute(reinterpret_cast<const void*>(&gemm128_kernel<0, 256, 1>),
                            hipFuncAttributeMaxDynamicSharedMemorySize, 73728);
        hipFuncSetAttribute(reinterpret_cast<const void*>(&gemm128_kernel<2, 256, 2>),
                            hipFuncAttributeMaxDynamicSharedMemorySize, 73728);
        hipFuncSetAttribute(reinterpret_cast<const void*>(&gemm128_kernel<2, 256, 4>),
                            hipFuncAttributeMaxDynamicSharedMemorySize, 73728);
        hipFuncSetAttribute(reinterpret_cast<const void*>(&gemm128_kernel<3, 256, 1>),
                            hipFuncAttributeMaxDynamicSharedMemorySize, 73728);
        attr_done = true;
    }

    // ---- workspace layout (bf16 elems; weight rows padded: 960->1024,
    //      1728->1792 so every GEMM N-tile has backing rows) ----
    const size_t PL = 8601600;
    const size_t offQ = 0, offPW = 786432, offKV = 1572864,
                 offPJ = 3293184, offF1 = 3883008, offF2 = 6242304;
    unsigned short* W = (unsigned short*)ws;
    char* act = ws + PL * 2 * L_LAYERS;                 // 68,812,800 B weights
    unsigned short* y_bf = (unsigned short*)act;        // 12544*768 bf16
    char* blk = act + (size_t)ROWS * CDIM * 2;
    unsigned short* q_bf  = (unsigned short*)(blk);                 // 12544*960
    unsigned short* r0_bf = (unsigned short*)(blk + 24084480);      // 3328*768 (pad rows)
    float*          pw_f  = (float*)        (blk + 29196288);       // 3136*960 f32
    unsigned short* r_bf  = (unsigned short*)(blk + 41238528);      // 3328*960 (pad rows)
    unsigned short* kv_bf = (unsigned short*)(blk + 47628288);      // 3136*1728
    unsigned short* o_bf  = (unsigned short*)(blk + 58466304);      // 12544*768
    unsigned short* h_bf  = (unsigned short*)(blk);                 // 12544*3072 (aliases, dead by then)
    unsigned short* z_bf  = y_bf;

    hipMemcpyAsync(xout, x_in, (size_t)ROWS * CDIM * sizeof(float),
                   hipMemcpyDeviceToDevice, stream);

    // ---- weight prep (fp32 KxN -> bf16 NxK), all layers via grid.z ----
    dim3 tb(32, 8);
    transpose_bf16_kernel<<<dim3(CNDIM / 32, CDIM / 32, L_LAYERS), tb, 0, stream>>>(
        q_w, W + offQ, CDIM, CNDIM, (size_t)CDIM * CNDIM, PL);
    transpose_bf16_kernel<<<dim3(CNDIM / 32, CDIM / 32, L_LAYERS), tb, 0, stream>>>(
        pw_w, W + offPW, CDIM, CNDIM, (size_t)CDIM * CNDIM, PL);
    transpose_bf16_kernel<<<dim3(CNDIM / 32, CNDIM / 32, L_LAYERS), tb, 0, stream>>>(
        k_w, W + offKV, CNDIM, CNDIM, (size_t)CNDIM * CNDIM, PL);
    transpose_bf16_kernel<<<dim3(CDIM / 32, CNDIM / 32, L_LAYERS), tb, 0, stream>>>(
        v_w, W + offKV + (size_t)CNDIM * CNDIM, CNDIM, CDIM, (size_t)CNDIM * CDIM, PL);
    transpose_bf16_kernel<<<dim3(CDIM / 32, CDIM / 32, L_LAYERS), tb, 0, stream>>>(
        proj_w, W + offPJ, CDIM, CDIM, (size_t)CDIM * CDIM, PL);
    transpose_bf16_kernel<<<dim3(HIDDIM / 32, CDIM / 32, L_LAYERS), tb, 0, stream>>>(
        fc1_w, W + offF1, CDIM, HIDDIM, (size_t)CDIM * HIDDIM, PL);
    transpose_bf16_kernel<<<dim3(CDIM / 32, HIDDIM / 32, L_LAYERS), tb, 0, stream>>>(
        fc2_w, W + offF2, HIDDIM, CDIM, (size_t)HIDDIM * CDIM, PL);

    for (int l = 0; l < L_LAYERS; l++) {
        const unsigned short* wl = W + (size_t)l * PL;
        // LN1 -> y
        ln_kernel<<<ROWS / 4, 256, 0, stream>>>(xout, ln1_g + l * CDIM, ln1_b + l * CDIM,
                                                y_bf, ROWS, CDIM, 1e-6f, 0);
        // q = y @ q_w  (12544 x 960 x 768), tiles 98 x 4 (N padded to 1024)
        gemm128_kernel<0, 256, 1><<<98 * 4, 512, 73728, stream>>>(
            y_bf, wl + offQ, nullptr, nullptr, q_bf, ROWS, CNDIM, CDIM, 98, 4);
        // depthwise conv reduce -> r0 (3136 x 768)
        dwconv_kernel<<<RROWS, 256, 0, stream>>>(y_bf, dw_w + (size_t)l * CDIM * 4,
                                                 dw_b + l * CDIM, r0_bf);
        // pw: r0 @ pw_w + b  (3136 x 960 x 768) -> fp32, tiles 25 x 8 (BN=128)
        gemm128_kernel<1, 128, 1><<<25 * 8, 512, 49152, stream>>>(
            r0_bf, wl + offPW, pw_b + l * CNDIM, pw_f, nullptr, RROWS, CNDIM, CDIM, 25, 8);
        // norm_act: LN(eps 1e-5) + GELU -> r
        ln_kernel<<<RROWS / 4, 256, 0, stream>>>(pw_f, lnr_g + l * CNDIM, lnr_b + l * CNDIM,
                                                 r_bf, RROWS, CNDIM, 1e-5f, 1);
        // fused kv = r @ [k_w | v_w]  (3136 x 1728 x 960), tiles 25 x 14 (BN=128)
        gemm128_kernel<0, 128, 1><<<25 * 14, 512, 49152, stream>>>(
            r_bf, wl + offKV, nullptr, nullptr, kv_bf, RROWS, KVN, CNDIM, 25, 14);
        // attention -> o (bf16), MFMA flash-style
        attn_kernel<<<BSZ * NHEAD, 512, 0, stream>>>(q_bf, kv_bf, o_bf);
        // x += o @ proj_w + proj_b, split-K 2 (12544 x 768 x 768), 98x3x2 blocks
        gemm128_kernel<2, 256, 2><<<98 * 3 * 2, 512, 73728, stream>>>(
            o_bf, wl + offPJ, proj_b + l * CDIM, xout, nullptr, ROWS, CDIM, CDIM, 98, 3);
        // LN2 -> z
        ln_kernel<<<ROWS / 4, 256, 0, stream>>>(xout, ln2_g + l * CDIM, ln2_b + l * CDIM,
                                                z_bf, ROWS, CDIM, 1e-6f, 0);
        // h = gelu(z @ fc1 + b)  (12544 x 3072 x 768), tiles 98 x 12
        gemm128_kernel<3, 256, 1><<<98 * 12, 512, 73728, stream>>>(
            z_bf, wl + offF1, fc1_b + l * HIDDIM, nullptr, h_bf, ROWS, HIDDIM, CDIM, 98, 12);
        // x += h @ fc2 + b, split-K 4 (12544 x 768 x 3072), 98x3x4 blocks
        gemm128_kernel<2, 256, 4><<<98 * 3 * 4, 512, 73728, stream>>>(
            h_bf, wl + offF2, fc2_b + l * CDIM, xout, nullptr, ROWS, CDIM, HIDDIM, 98, 3);
    }
}

// Round 6
// 1548.899 us; speedup vs baseline: 2.6458x; 2.6458x over previous
//
#include <hip/hip_runtime.h>
#include <hip/hip_bf16.h>
#include <math.h>

#define L_LAYERS 4
#define BSZ 64
#define NTOK 196
#define CDIM 768
#define CNDIM 960
#define HIDDIM 3072
#define NHEAD 12
#define HD 64
#define HDK 80
#define MRED 49
#define ROWS (BSZ*NTOK)    /* 12544 */
#define RROWS (BSZ*MRED)   /* 3136 */
#define KVN 1728           /* 960 + 768 fused k|v output cols */

typedef __bf16 bf16x8 __attribute__((ext_vector_type(8)));
typedef float f32x4 __attribute__((ext_vector_type(4)));
typedef unsigned short u16x4 __attribute__((ext_vector_type(4)));

static __device__ inline float bf2f(unsigned short u) {
    unsigned int x = ((unsigned int)u) << 16;
    return __builtin_bit_cast(float, x);
}
static __device__ inline unsigned short f2bf(float f) {
    return __builtin_bit_cast(unsigned short, __float2bfloat16(f));
}
static __device__ inline unsigned int pack2bf(float lo, float hi) {
    return (unsigned int)f2bf(lo) | ((unsigned int)f2bf(hi) << 16);
}
// tanh-form GELU: x*sigmoid(1.5958x + 0.07135x^3); |err vs exact| ~3e-4
static __device__ inline float gelu_f(float x) {
    float t = x * (1.5957691216f + 0.0713548162f * x * x);
    return x * __builtin_amdgcn_rcpf(1.0f + __expf(-t));
}

// async 16B global -> LDS (wave-uniform LDS base + lane*16)
#define GLLDS16(gsrc, ldst)                                                        \
    __builtin_amdgcn_global_load_lds(                                              \
        (const __attribute__((address_space(1))) unsigned int*)(const void*)(gsrc),\
        (__attribute__((address_space(3))) unsigned int*)(void*)(ldst), 16, 0, 0)

// ---------------------------------------------------------------------------
// Weight prep: src fp32 (K x N) row-major -> dst bf16 (N x K) row-major.
// ---------------------------------------------------------------------------
__global__ void transpose_bf16_kernel(const float* __restrict__ src,
                                      unsigned short* __restrict__ dst,
                                      int K, int N, size_t srcLS, size_t dstLS) {
    __shared__ float tile[32][33];
    const float* s = src + (size_t)blockIdx.z * srcLS;
    unsigned short* d = dst + (size_t)blockIdx.z * dstLS;
    int k0 = blockIdx.y * 32, n0 = blockIdx.x * 32;
#pragma unroll
    for (int i = 0; i < 4; i++) {
        int k = k0 + threadIdx.y + i * 8, n = n0 + threadIdx.x;
        if (k < K && n < N) tile[threadIdx.y + i * 8][threadIdx.x] = s[(size_t)k * N + n];
    }
    __syncthreads();
#pragma unroll
    for (int i = 0; i < 4; i++) {
        int n = n0 + threadIdx.y + i * 8, k = k0 + threadIdx.x;
        if (n < N && k < K) d[(size_t)n * K + k] = f2bf(tile[threadIdx.x][threadIdx.y + i * 8]);
    }
}

// ---------------------------------------------------------------------------
// LayerNorm (one wave per row), optional GELU, bf16 output.
// ---------------------------------------------------------------------------
__global__ void ln_kernel(const float* __restrict__ x, const float* __restrict__ g,
                          const float* __restrict__ b, unsigned short* __restrict__ y,
                          int M, int C, float eps, int do_gelu) {
    int row = blockIdx.x * 4 + (threadIdx.x >> 6);
    int lane = threadIdx.x & 63;
    if (row >= M) return;
    const float* xr = x + (size_t)row * C;
    float s = 0.f, ss = 0.f;
    for (int c = lane; c < C; c += 64) { float v = xr[c]; s += v; ss += v * v; }
#pragma unroll
    for (int off = 32; off; off >>= 1) { s += __shfl_down(s, off); ss += __shfl_down(ss, off); }
    s = __shfl(s, 0); ss = __shfl(ss, 0);
    float mean = s / (float)C;
    float var = ss / (float)C - mean * mean;
    float rstd = rsqrtf(var + eps);
    unsigned short* yr = y + (size_t)row * C;
    for (int c = lane; c < C; c += 64) {
        float v = (xr[c] - mean) * rstd * g[c] + b[c];
        if (do_gelu) v = gelu_f(v);
        yr[c] = f2bf(v);
    }
}

// ---------------------------------------------------------------------------
// Depthwise 2x2 stride-2 conv on the token grid (14x14 -> 7x7), bf16 in/out.
// ---------------------------------------------------------------------------
__global__ void dwconv_kernel(const unsigned short* __restrict__ y,
                              const float* __restrict__ w,
                              const float* __restrict__ bias,
                              unsigned short* __restrict__ r0) {
    int bm = blockIdx.x;
    int b = bm / MRED, m = bm % MRED;
    int i = m / 7, j = m % 7;
    int r00 = b * NTOK + (2 * i) * 14 + 2 * j;
    for (int c = threadIdx.x; c < CDIM; c += 256) {
        float acc = bias[c];
        acc += bf2f(y[(size_t)(r00)      * CDIM + c]) * w[c * 4 + 0];
        acc += bf2f(y[(size_t)(r00 + 1)  * CDIM + c]) * w[c * 4 + 1];
        acc += bf2f(y[(size_t)(r00 + 14) * CDIM + c]) * w[c * 4 + 2];
        acc += bf2f(y[(size_t)(r00 + 15) * CDIM + c]) * w[c * 4 + 3];
        r0[(size_t)bm * CDIM + c] = f2bf(acc);
    }
}

// ---------------------------------------------------------------------------
// MFMA GEMM: 128x128 tile, BK=64, 8 waves (2M x 4N), per-wave 64x32 output
// (acc[4][2] = 32 AGPR). Ring-2 LDS: 2 slots x (A 16KB | B 16KB) = 64KB ->
// 2 blocks/CU (16 waves, __launch_bounds__(512,4)).
// BK=64 halves barrier/drain events vs BK=32 and doubles the per-iter MFMA
// body (~1024 cy), so the end-of-iter vmcnt(0) drain is mostly covered by
// body + co-resident block. Grids double vs BN=256 (fc1 2352, fc2/proj 588).
// LDS rows are 128B (8 chunks): XOR swizzle chunk ^= (row&7) breaks the
// all-rows-same-bank conflict; global_load_lds writes linearly, so the
// GLOBAL source chunk is inverse-swizzled (involution), and ds_read applies
// the same XOR (rule #21: both sides or neither).
// MODE 0: bf16 = acc ; 1: fp32 = acc+bias ; 2: fp32 += acc+bias ;
// 3: bf16 = gelu(acc+bias).  Epilogue masks gr<M, gc<N (padded tiles).
// ---------------------------------------------------------------------------
template <int MODE>
__global__ __launch_bounds__(512, 4) void gemm128_kernel(
    const unsigned short* __restrict__ A,
    const unsigned short* __restrict__ Bt,
    const float* __restrict__ bias,
    float* __restrict__ outF,
    unsigned short* __restrict__ outB,
    int M, int N, int K, int NR, int NC) {
    extern __shared__ __align__(16) char sb[];   // 2 slots x 32KB

    // XCD-aware tile swizzle: groups of 8 row-tiles x NC col-tiles
    int id = blockIdx.x;
    int gsize = 8 * NC;
    int g = id / gsize;
    int local = id - g * gsize;
    int rbase = g * 8;
    int Gg = NR - rbase; if (Gg > 8) Gg = 8;
    int col = local / Gg;
    int row = rbase + (local - col * Gg);
    int m0 = row * 128, n0 = col * 128;

    int tid = threadIdx.x;
    int w = tid >> 6, lane = tid & 63, quad = lane >> 4, l16 = lane & 15;
    int wm = w >> 2, wn = w & 3;        // 2 x 4 wave grid

    // ---- staging sources: thread t -> row r=t>>3 (and r+64), phys chunk
    //      p=t&7; logical source chunk qc = p ^ (r&7) (inverse swizzle) ----
    int r = tid >> 3;
    int qc = (tid & 7) ^ (r & 7);
    const unsigned short* aS0 = A  + (size_t)(m0 + r) * K + qc * 8;
    const unsigned short* aS1 = A  + (size_t)(m0 + r + 64) * K + qc * 8;
    const unsigned short* bS0 = Bt + (size_t)(n0 + r) * K + qc * 8;
    const unsigned short* bS1 = Bt + (size_t)(n0 + r + 64) * K + qc * 8;

    // ---- read-side fragment byte offsets (swizzled) ----
    // frag row R (R&7 == l16&7), kk-half, quad: chunk = (kk*4+quad)^(R&7)
    int s7 = l16 & 7;
    int sq0 = ((0 + quad) ^ s7) * 16;
    int sq1 = ((4 + quad) ^ s7) * 16;
    int aBase = (wm * 64 + l16) * 128;            // + mi*2048 + slot
    int bBase = 16384 + (wn * 32 + l16) * 128;    // + ni*2048 + slot

    f32x4 zero4 = {0.f, 0.f, 0.f, 0.f};
    f32x4 acc[4][2];
#pragma unroll
    for (int mi = 0; mi < 4; mi++)
#pragma unroll
        for (int ni = 0; ni < 2; ni++) acc[mi][ni] = zero4;

    int NT = K >> 6;

#define STAGE64(slotptr, tt)                                     \
    do {                                                         \
        int ko_ = (tt) * 64;                                     \
        GLLDS16(aS0 + ko_, (slotptr) + w * 1024);                \
        GLLDS16(aS1 + ko_, (slotptr) + 8192  + w * 1024);        \
        GLLDS16(bS0 + ko_, (slotptr) + 16384 + w * 1024);        \
        GLLDS16(bS1 + ko_, (slotptr) + 24576 + w * 1024);        \
    } while (0)

    // prologue: stage tile 0
    STAGE64(sb, 0);
    asm volatile("s_waitcnt vmcnt(0)" ::: "memory");
    __builtin_amdgcn_s_barrier();

    for (int t = 0; t < NT; ++t) {
        char* sc = sb + (size_t)(t & 1) * 32768;
        if (t + 1 < NT) {
            char* sp = sb + (size_t)((t + 1) & 1) * 32768;
            STAGE64(sp, t + 1);
        }
        bf16x8 af[4], bfr[2];
        // ---- kk = 0 ----
#pragma unroll
        for (int mi = 0; mi < 4; mi++)
            af[mi] = *(const bf16x8*)(sc + aBase + mi * 2048 + sq0);
#pragma unroll
        for (int ni = 0; ni < 2; ni++)
            bfr[ni] = *(const bf16x8*)(sc + bBase + ni * 2048 + sq0);
        __builtin_amdgcn_s_setprio(1);
#pragma unroll
        for (int mi = 0; mi < 4; mi++)
#pragma unroll
            for (int ni = 0; ni < 2; ni++)
                acc[mi][ni] = __builtin_amdgcn_mfma_f32_16x16x32_bf16(
                    af[mi], bfr[ni], acc[mi][ni], 0, 0, 0);
        __builtin_amdgcn_s_setprio(0);
        // ---- kk = 1 ----
#pragma unroll
        for (int mi = 0; mi < 4; mi++)
            af[mi] = *(const bf16x8*)(sc + aBase + mi * 2048 + sq1);
#pragma unroll
        for (int ni = 0; ni < 2; ni++)
            bfr[ni] = *(const bf16x8*)(sc + bBase + ni * 2048 + sq1);
        __builtin_amdgcn_s_setprio(1);
#pragma unroll
        for (int mi = 0; mi < 4; mi++)
#pragma unroll
            for (int ni = 0; ni < 2; ni++)
                acc[mi][ni] = __builtin_amdgcn_mfma_f32_16x16x32_bf16(
                    af[mi], bfr[ni], acc[mi][ni], 0, 0, 0);
        __builtin_amdgcn_s_setprio(0);
        asm volatile("s_waitcnt vmcnt(0)" ::: "memory");
        __builtin_amdgcn_s_barrier();
    }
#undef STAGE64

    // --- epilogue: repack each wave's 16x32 slices through private LDS ---
    __syncthreads();
    float* eld = (float*)(sb + w * 2048);
    int colbase = n0 + wn * 32;
#pragma unroll
    for (int mi = 0; mi < 4; mi++) {
#pragma unroll
        for (int ni = 0; ni < 2; ni++)
#pragma unroll
            for (int rr = 0; rr < 4; rr++)
                eld[(quad * 4 + rr) * 32 + ni * 16 + l16] = acc[mi][ni][rr];
        int rowb = m0 + wm * 64 + mi * 16;
#pragma unroll
        for (int p = 0; p < 2; p++) {
            int r2 = p * 8 + (lane >> 3);
            int c2 = (lane & 7) * 4;
            int gr = rowb + r2, gc = colbase + c2;
            if (gr < M && gc < N) {
                f32x4 v4 = *(f32x4*)(eld + r2 * 32 + c2);
                if (MODE == 0) {
                    u16x4 h;
#pragma unroll
                    for (int e = 0; e < 4; e++) h[e] = f2bf(v4[e]);
                    *(u16x4*)(outB + (size_t)gr * N + gc) = h;
                } else {
                    f32x4 b4 = *(const f32x4*)(bias + gc);
                    if (MODE == 1) {
                        *(f32x4*)(outF + (size_t)gr * N + gc) = v4 + b4;
                    } else if (MODE == 2) {
                        f32x4 o4 = *(f32x4*)(outF + (size_t)gr * N + gc);
                        *(f32x4*)(outF + (size_t)gr * N + gc) = o4 + v4 + b4;
                    } else {  // MODE 3
                        u16x4 h;
#pragma unroll
                        for (int e = 0; e < 4; e++) h[e] = f2bf(gelu_f(v4[e] + b4[e]));
                        *(u16x4*)(outB + (size_t)gr * N + gc) = h;
                    }
                }
            }
        }
    }
}

// ---------------------------------------------------------------------------
// MFMA attention. One block per (b,h), 8 waves. Swapped-operand QK^T:
// S^T = mfma(A=K_frag, B=Q_frag) so the k-reduction is in-lane + 2 shfl_xor.
// V staged in LDS pre-permuted to the PV B-operand k-order, so the C-layout
// P^T fragments feed PV mfma directly (no cross-lane shuffles):
//   V2[d][c], c = 32s + 8q + j  ->  ktilde = 32s + 16*(j>=4) + 4q + (j&3)
// K_lds[64][96] (d-pad zeroed); O^T bounced via per-wave LDS tile (stride 72)
// to coalesced 16B stores. k>=49 masked at softmax; V2 pad rows zero.
// ---------------------------------------------------------------------------
__global__ __launch_bounds__(512, 4) void attn_kernel(
    const unsigned short* __restrict__ qb,   // (ROWS, CNDIM)
    const unsigned short* __restrict__ kv,   // (RROWS, KVN)
    unsigned short* __restrict__ ob) {       // (ROWS, CDIM)
    __shared__ __align__(16) unsigned short Ks[64 * 96];    // 12288 B
    __shared__ __align__(16) unsigned short V2[64 * 136];   // 17408 B (136 pad, cols 0..127 used)
    __shared__ __align__(16) unsigned short Os[8 * 16 * 72]; // 18432 B per-wave bounce

    int bh = blockIdx.x;
    int b = bh / NHEAD, h = bh % NHEAD;
    int tid = threadIdx.x;

    // --- zero K d-pad (cols 80..95, rows 0..48); disjoint from staged region ---
    for (int idx = tid; idx < 49 * 8; idx += 512) {
        int m = idx >> 3, c = idx & 7;
        ((unsigned int*)Ks)[m * 48 + 40 + c] = 0u;
    }
    // --- stage K rows: K_lds[m][d] = kv[b*49+m][h*80+d], 16B chunks ---
    for (int idx = tid; idx < 49 * 10; idx += 512) {
        int m = idx / 10, c = idx % 10;
        bf16x8 v = *(const bf16x8*)(kv + (size_t)(b * MRED + m) * KVN + h * HDK + c * 8);
        *(bf16x8*)(Ks + m * 96 + c * 8) = v;
    }
    // --- stage V pre-permuted: V2[d][c] = V[ktilde(c)][d] or 0 ---
    for (int idx = tid; idx < 64 * 128; idx += 512) {
        int d = idx >> 7, c = idx & 127;
        int s = c >> 5, q = (c >> 3) & 3, j = c & 7;
        int kt = s * 32 + ((j >> 2) << 4) + q * 4 + (j & 3);
        unsigned short val = 0;
        if (kt < MRED) val = kv[(size_t)(b * MRED + kt) * KVN + 960 + h * HD + d];
        V2[d * 136 + c] = val;
    }
    __syncthreads();

    int wv = tid >> 6, lane = tid & 63, quad = lane >> 4, l16 = lane & 15;
    unsigned short* Ow = Os + wv * 16 * 72;
    const float scale = 0.11180339887498949f;  // 1/sqrt(80)
    f32x4 zero4 = {0.f, 0.f, 0.f, 0.f};

#pragma unroll
    for (int gi = 0; gi < 2; ++gi) {
        int qg = wv + gi * 8;
        if (qg >= 13) break;
        // Q B-fragments (global, L2/L3-resident): B[d][q], d = quad*8+j
        const unsigned short* qrow =
            qb + (size_t)(b * NTOK + qg * 16 + l16) * CNDIM + h * HDK + quad * 8;
        bf16x8 bq0 = *(const bf16x8*)(qrow);
        bf16x8 bq1 = *(const bf16x8*)(qrow + 32);
        bf16x8 bq2 = *(const bf16x8*)(qrow + 64);

        // S^T = K @ Q^T : 4 k-frags x 3 K32-steps
        f32x4 sf[4];
#pragma unroll
        for (int kf = 0; kf < 4; kf++) sf[kf] = zero4;
#pragma unroll
        for (int kf = 0; kf < 4; kf++) {
            const unsigned short* kr = Ks + (kf * 16 + l16) * 96 + quad * 8;
            sf[kf] = __builtin_amdgcn_mfma_f32_16x16x32_bf16(
                *(const bf16x8*)(kr), bq0, sf[kf], 0, 0, 0);
            sf[kf] = __builtin_amdgcn_mfma_f32_16x16x32_bf16(
                *(const bf16x8*)(kr + 32), bq1, sf[kf], 0, 0, 0);
            sf[kf] = __builtin_amdgcn_mfma_f32_16x16x32_bf16(
                *(const bf16x8*)(kr + 64), bq2, sf[kf], 0, 0, 0);
        }

        // softmax over k (rows of S^T): lane holds k = 16kf + 4quad + r, col q=l16
        float p[4][4];
        float mx = -1e30f;
#pragma unroll
        for (int kf = 0; kf < 4; kf++)
#pragma unroll
            for (int r = 0; r < 4; r++) {
                float v = sf[kf][r] * scale;
                if (kf == 3) {
                    // k = 48 + 4*quad + r valid only for quad==0 && r==0
                    v = (r == 0 && quad == 0) ? v : -1e30f;
                }
                p[kf][r] = v;
                mx = fmaxf(mx, v);
            }
        mx = fmaxf(mx, __shfl_xor(mx, 16));
        mx = fmaxf(mx, __shfl_xor(mx, 32));
        float sum = 0.f;
#pragma unroll
        for (int kf = 0; kf < 4; kf++)
#pragma unroll
            for (int r = 0; r < 4; r++) {
                float e = __expf(p[kf][r] - mx);
                p[kf][r] = e;
                sum += e;
            }
        sum += __shfl_xor(sum, 16);
        sum += __shfl_xor(sum, 32);
        float inv = 1.0f / sum;
#pragma unroll
        for (int kf = 0; kf < 4; kf++)
#pragma unroll
            for (int r = 0; r < 4; r++) p[kf][r] *= inv;

        // pack P^T to bf16 pairs (r0,r1),(r2,r3) per frag
        unsigned int W[4][2];
#pragma unroll
        for (int kf = 0; kf < 4; kf++) {
            W[kf][0] = pack2bf(p[kf][0], p[kf][1]);
            W[kf][1] = pack2bf(p[kf][2], p[kf][3]);
        }

        // PV: O^T = V2 @ P : 4 d-frags x 2 K32-steps (V2 pre-permuted)
        f32x4 oacc[4];
#pragma unroll
        for (int df = 0; df < 4; df++) oacc[df] = zero4;
#pragma unroll
        for (int s = 0; s < 2; s++) {
            union { unsigned int u[4]; bf16x8 v; } bb;
            bb.u[0] = W[2 * s][0];
            bb.u[1] = W[2 * s][1];
            bb.u[2] = W[2 * s + 1][0];
            bb.u[3] = W[2 * s + 1][1];
#pragma unroll
            for (int df = 0; df < 4; df++) {
                const unsigned short* vr = V2 + (df * 16 + l16) * 136 + s * 32 + quad * 8;
                oacc[df] = __builtin_amdgcn_mfma_f32_16x16x32_bf16(
                    *(const bf16x8*)(vr), bb.v, oacc[df], 0, 0, 0);
            }
        }

        // O^T frags (row d = 16df+4quad+r, col q = l16) -> per-wave LDS bounce
#pragma unroll
        for (int df = 0; df < 4; df++) {
#pragma unroll
            for (int wp = 0; wp < 2; wp++) {
                unsigned int pk = pack2bf(oacc[df][2 * wp], oacc[df][2 * wp + 1]);
                *(unsigned int*)(Ow + l16 * 72 + df * 16 + quad * 4 + 2 * wp) = pk;
            }
        }
        // readback (same wave; compiler inserts lgkm wait) -> coalesced stores
        int q = lane >> 2, cch = lane & 3;
        int grow = qg * 16 + q;
        if (grow < NTOK) {
            unsigned short* dst = ob + (size_t)(b * NTOK + grow) * CDIM + h * HD + cch * 8;
            bf16x8 v0 = *(const bf16x8*)(Ow + q * 72 + cch * 8);
            bf16x8 v1 = *(const bf16x8*)(Ow + q * 72 + cch * 8 + 32);
            *(bf16x8*)(dst) = v0;
            *(bf16x8*)(dst + 32) = v1;
        }
    }
}

// ---------------------------------------------------------------------------

extern "C" void kernel_launch(void* const* d_in, const int* in_sizes, int n_in,
                              void* d_out, int out_size, void* d_ws, size_t ws_size,
                              hipStream_t stream) {
    (void)in_sizes; (void)n_in; (void)out_size; (void)ws_size;
    const float* x_in   = (const float*)d_in[0];
    const float* q_w    = (const float*)d_in[1];
    const float* dw_w   = (const float*)d_in[2];
    const float* dw_b   = (const float*)d_in[3];
    const float* pw_w   = (const float*)d_in[4];
    const float* pw_b   = (const float*)d_in[5];
    const float* lnr_g  = (const float*)d_in[6];
    const float* lnr_b  = (const float*)d_in[7];
    const float* k_w    = (const float*)d_in[8];
    const float* v_w    = (const float*)d_in[9];
    const float* proj_w = (const float*)d_in[10];
    const float* proj_b = (const float*)d_in[11];
    const float* ln1_g  = (const float*)d_in[12];
    const float* ln1_b  = (const float*)d_in[13];
    const float* ln2_g  = (const float*)d_in[14];
    const float* ln2_b  = (const float*)d_in[15];
    const float* fc1_w  = (const float*)d_in[16];
    const float* fc1_b  = (const float*)d_in[17];
    const float* fc2_w  = (const float*)d_in[18];
    const float* fc2_b  = (const float*)d_in[19];
    float* xout = (float*)d_out;
    char* ws = (char*)d_ws;

    // dynamic-LDS opt-in (64KB ring-2)
    static bool attr_done = false;
    if (!attr_done) {
        hipFuncSetAttribute(reinterpret_cast<const void*>(&gemm128_kernel<0>),
                            hipFuncAttributeMaxDynamicSharedMemorySize, 65536);
        hipFuncSetAttribute(reinterpret_cast<const void*>(&gemm128_kernel<1>),
                            hipFuncAttributeMaxDynamicSharedMemorySize, 65536);
        hipFuncSetAttribute(reinterpret_cast<const void*>(&gemm128_kernel<2>),
                            hipFuncAttributeMaxDynamicSharedMemorySize, 65536);
        hipFuncSetAttribute(reinterpret_cast<const void*>(&gemm128_kernel<3>),
                            hipFuncAttributeMaxDynamicSharedMemorySize, 65536);
        attr_done = true;
    }

    // ---- workspace layout (bf16 elems; weight rows padded: 960->1024,
    //      1728->1792 so every GEMM N-tile has backing rows) ----
    const size_t PL = 8601600;
    const size_t offQ = 0, offPW = 786432, offKV = 1572864,
                 offPJ = 3293184, offF1 = 3883008, offF2 = 6242304;
    unsigned short* W = (unsigned short*)ws;
    char* act = ws + PL * 2 * L_LAYERS;                 // 68,812,800 B weights
    unsigned short* y_bf = (unsigned short*)act;        // 12544*768 bf16
    char* blk = act + (size_t)ROWS * CDIM * 2;
    unsigned short* q_bf  = (unsigned short*)(blk);                 // 12544*960
    unsigned short* r0_bf = (unsigned short*)(blk + 24084480);      // 3328*768 (pad rows)
    float*          pw_f  = (float*)        (blk + 29196288);       // 3136*960 f32
    unsigned short* r_bf  = (unsigned short*)(blk + 41238528);      // 3328*960 (pad rows)
    unsigned short* kv_bf = (unsigned short*)(blk + 47628288);      // 3136*1728
    unsigned short* o_bf  = (unsigned short*)(blk + 58466304);      // 12544*768
    unsigned short* h_bf  = (unsigned short*)(blk);                 // 12544*3072 (aliases, dead by then)
    unsigned short* z_bf  = y_bf;

    hipMemcpyAsync(xout, x_in, (size_t)ROWS * CDIM * sizeof(float),
                   hipMemcpyDeviceToDevice, stream);

    // ---- weight prep (fp32 KxN -> bf16 NxK), all layers via grid.z ----
    dim3 tb(32, 8);
    transpose_bf16_kernel<<<dim3(CNDIM / 32, CDIM / 32, L_LAYERS), tb, 0, stream>>>(
        q_w, W + offQ, CDIM, CNDIM, (size_t)CDIM * CNDIM, PL);
    transpose_bf16_kernel<<<dim3(CNDIM / 32, CDIM / 32, L_LAYERS), tb, 0, stream>>>(
        pw_w, W + offPW, CDIM, CNDIM, (size_t)CDIM * CNDIM, PL);
    transpose_bf16_kernel<<<dim3(CNDIM / 32, CNDIM / 32, L_LAYERS), tb, 0, stream>>>(
        k_w, W + offKV, CNDIM, CNDIM, (size_t)CNDIM * CNDIM, PL);
    transpose_bf16_kernel<<<dim3(CDIM / 32, CNDIM / 32, L_LAYERS), tb, 0, stream>>>(
        v_w, W + offKV + (size_t)CNDIM * CNDIM, CNDIM, CDIM, (size_t)CNDIM * CDIM, PL);
    transpose_bf16_kernel<<<dim3(CDIM / 32, CDIM / 32, L_LAYERS), tb, 0, stream>>>(
        proj_w, W + offPJ, CDIM, CDIM, (size_t)CDIM * CDIM, PL);
    transpose_bf16_kernel<<<dim3(HIDDIM / 32, CDIM / 32, L_LAYERS), tb, 0, stream>>>(
        fc1_w, W + offF1, CDIM, HIDDIM, (size_t)CDIM * HIDDIM, PL);
    transpose_bf16_kernel<<<dim3(CDIM / 32, HIDDIM / 32, L_LAYERS), tb, 0, stream>>>(
        fc2_w, W + offF2, HIDDIM, CDIM, (size_t)HIDDIM * CDIM, PL);

    for (int l = 0; l < L_LAYERS; l++) {
        const unsigned short* wl = W + (size_t)l * PL;
        // LN1 -> y
        ln_kernel<<<ROWS / 4, 256, 0, stream>>>(xout, ln1_g + l * CDIM, ln1_b + l * CDIM,
                                                y_bf, ROWS, CDIM, 1e-6f, 0);
        // q = y @ q_w  (12544 x 960 x 768), tiles 98 x 8 (N padded to 1024)
        gemm128_kernel<0><<<98 * 8, 512, 65536, stream>>>(
            y_bf, wl + offQ, nullptr, nullptr, q_bf, ROWS, CNDIM, CDIM, 98, 8);
        // depthwise conv reduce -> r0 (3136 x 768)
        dwconv_kernel<<<RROWS, 256, 0, stream>>>(y_bf, dw_w + (size_t)l * CDIM * 4,
                                                 dw_b + l * CDIM, r0_bf);
        // pw: r0 @ pw_w + b  (3136 x 960 x 768) -> fp32, tiles 25 x 8
        gemm128_kernel<1><<<25 * 8, 512, 65536, stream>>>(
            r0_bf, wl + offPW, pw_b + l * CNDIM, pw_f, nullptr, RROWS, CNDIM, CDIM, 25, 8);
        // norm_act: LN(eps 1e-5) + GELU -> r
        ln_kernel<<<RROWS / 4, 256, 0, stream>>>(pw_f, lnr_g + l * CNDIM, lnr_b + l * CNDIM,
                                                 r_bf, RROWS, CNDIM, 1e-5f, 1);
        // fused kv = r @ [k_w | v_w]  (3136 x 1728 x 960), tiles 25 x 14
        gemm128_kernel<0><<<25 * 14, 512, 65536, stream>>>(
            r_bf, wl + offKV, nullptr, nullptr, kv_bf, RROWS, KVN, CNDIM, 25, 14);
        // attention -> o (bf16), MFMA flash-style
        attn_kernel<<<BSZ * NHEAD, 512, 0, stream>>>(q_bf, kv_bf, o_bf);
        // x += o @ proj_w + proj_b  (12544 x 768 x 768), tiles 98 x 6
        gemm128_kernel<2><<<98 * 6, 512, 65536, stream>>>(
            o_bf, wl + offPJ, proj_b + l * CDIM, xout, nullptr, ROWS, CDIM, CDIM, 98, 6);
        // LN2 -> z
        ln_kernel<<<ROWS / 4, 256, 0, stream>>>(xout, ln2_g + l * CDIM, ln2_b + l * CDIM,
                                                z_bf, ROWS, CDIM, 1e-6f, 0);
        // h = gelu(z @ fc1 + b)  (12544 x 3072 x 768), tiles 98 x 24
        gemm128_kernel<3><<<98 * 24, 512, 65536, stream>>>(
            z_bf, wl + offF1, fc1_b + l * HIDDIM, nullptr, h_bf, ROWS, HIDDIM, CDIM, 98, 24);
        // x += h @ fc2 + b  (12544 x 768 x 3072), tiles 98 x 6
        gemm128_kernel<2><<<98 * 6, 512, 65536, stream>>>(
            h_bf, wl + offF2, fc2_b + l * CDIM, xout, nullptr, ROWS, CDIM, HIDDIM, 98, 6);
    }
}

// Round 7
// 1454.903 us; speedup vs baseline: 2.8168x; 1.0646x over previous
//
#include <hip/hip_runtime.h>
#include <hip/hip_bf16.h>
#include <math.h>

#define L_LAYERS 4
#define BSZ 64
#define NTOK 196
#define CDIM 768
#define CNDIM 960
#define HIDDIM 3072
#define NHEAD 12
#define HD 64
#define HDK 80
#define MRED 49
#define ROWS (BSZ*NTOK)    /* 12544 */
#define RROWS (BSZ*MRED)   /* 3136 */
#define KVN 1728           /* 960 + 768 fused k|v output cols */

typedef __bf16 bf16x8 __attribute__((ext_vector_type(8)));
typedef float f32x4 __attribute__((ext_vector_type(4)));
typedef unsigned short u16x4 __attribute__((ext_vector_type(4)));

static __device__ inline float bf2f(unsigned short u) {
    unsigned int x = ((unsigned int)u) << 16;
    return __builtin_bit_cast(float, x);
}
static __device__ inline unsigned short f2bf(float f) {
    return __builtin_bit_cast(unsigned short, __float2bfloat16(f));
}
static __device__ inline unsigned int pack2bf(float lo, float hi) {
    return (unsigned int)f2bf(lo) | ((unsigned int)f2bf(hi) << 16);
}
// tanh-form GELU: x*sigmoid(1.5958x + 0.07135x^3); |err vs exact| ~3e-4
static __device__ inline float gelu_f(float x) {
    float t = x * (1.5957691216f + 0.0713548162f * x * x);
    return x * __builtin_amdgcn_rcpf(1.0f + __expf(-t));
}

// async 16B global -> LDS (wave-uniform LDS base + lane*16)
#define GLLDS16(gsrc, ldst)                                                        \
    __builtin_amdgcn_global_load_lds(                                              \
        (const __attribute__((address_space(1))) unsigned int*)(const void*)(gsrc),\
        (__attribute__((address_space(3))) unsigned int*)(void*)(ldst), 16, 0, 0)

// ---------------------------------------------------------------------------
// Weight prep: src fp32 (K x N) row-major -> dst bf16 (N x K) row-major.
// ---------------------------------------------------------------------------
__global__ void transpose_bf16_kernel(const float* __restrict__ src,
                                      unsigned short* __restrict__ dst,
                                      int K, int N, size_t srcLS, size_t dstLS) {
    __shared__ float tile[32][33];
    const float* s = src + (size_t)blockIdx.z * srcLS;
    unsigned short* d = dst + (size_t)blockIdx.z * dstLS;
    int k0 = blockIdx.y * 32, n0 = blockIdx.x * 32;
#pragma unroll
    for (int i = 0; i < 4; i++) {
        int k = k0 + threadIdx.y + i * 8, n = n0 + threadIdx.x;
        if (k < K && n < N) tile[threadIdx.y + i * 8][threadIdx.x] = s[(size_t)k * N + n];
    }
    __syncthreads();
#pragma unroll
    for (int i = 0; i < 4; i++) {
        int n = n0 + threadIdx.y + i * 8, k = k0 + threadIdx.x;
        if (n < N && k < K) d[(size_t)n * K + k] = f2bf(tile[threadIdx.x][threadIdx.y + i * 8]);
    }
}

// ---------------------------------------------------------------------------
// LayerNorm generic (one wave per row, two-pass), optional GELU, bf16 out.
// Used only for C=960 (small lnr op).
// ---------------------------------------------------------------------------
__global__ void ln_kernel(const float* __restrict__ x, const float* __restrict__ g,
                          const float* __restrict__ b, unsigned short* __restrict__ y,
                          int M, int C, float eps, int do_gelu) {
    int row = blockIdx.x * 4 + (threadIdx.x >> 6);
    int lane = threadIdx.x & 63;
    if (row >= M) return;
    const float* xr = x + (size_t)row * C;
    float s = 0.f, ss = 0.f;
    for (int c = lane; c < C; c += 64) { float v = xr[c]; s += v; ss += v * v; }
#pragma unroll
    for (int off = 32; off; off >>= 1) { s += __shfl_down(s, off); ss += __shfl_down(ss, off); }
    s = __shfl(s, 0); ss = __shfl(ss, 0);
    float mean = s / (float)C;
    float var = ss / (float)C - mean * mean;
    float rstd = rsqrtf(var + eps);
    unsigned short* yr = y + (size_t)row * C;
    for (int c = lane; c < C; c += 64) {
        float v = (xr[c] - mean) * rstd * g[c] + b[c];
        if (do_gelu) v = gelu_f(v);
        yr[c] = f2bf(v);
    }
}

// ---------------------------------------------------------------------------
// LayerNorm C=768, single-pass register-resident: 3 x f32x4 per lane,
// butterfly reduce, normalize from regs. Halves the f32 read traffic of the
// two-pass version and vectorizes loads/stores (G13).
// ---------------------------------------------------------------------------
__global__ void ln768_kernel(const float* __restrict__ x, const float* __restrict__ g,
                             const float* __restrict__ b, unsigned short* __restrict__ y,
                             int M, float eps) {
    int row = blockIdx.x * 4 + (threadIdx.x >> 6);
    int lane = threadIdx.x & 63;
    if (row >= M) return;
    const float* xr = x + (size_t)row * 768;
    f32x4 v[3];
    float s = 0.f, ss = 0.f;
#pragma unroll
    for (int j = 0; j < 3; j++) {
        v[j] = *(const f32x4*)(xr + j * 256 + lane * 4);
#pragma unroll
        for (int e = 0; e < 4; e++) { s += v[j][e]; ss += v[j][e] * v[j][e]; }
    }
#pragma unroll
    for (int off = 32; off; off >>= 1) { s += __shfl_xor(s, off); ss += __shfl_xor(ss, off); }
    const float invC = 1.0f / 768.0f;
    float mean = s * invC;
    float var = ss * invC - mean * mean;
    float rstd = rsqrtf(var + eps);
    unsigned short* yr = y + (size_t)row * 768;
#pragma unroll
    for (int j = 0; j < 3; j++) {
        f32x4 gv = *(const f32x4*)(g + j * 256 + lane * 4);
        f32x4 bv = *(const f32x4*)(b + j * 256 + lane * 4);
        u16x4 h;
#pragma unroll
        for (int e = 0; e < 4; e++)
            h[e] = f2bf((v[j][e] - mean) * rstd * gv[e] + bv[e]);
        *(u16x4*)(yr + j * 256 + lane * 4) = h;
    }
}

// ---------------------------------------------------------------------------
// Depthwise 2x2 stride-2 conv on the token grid (14x14 -> 7x7), bf16 in/out.
// ---------------------------------------------------------------------------
__global__ void dwconv_kernel(const unsigned short* __restrict__ y,
                              const float* __restrict__ w,
                              const float* __restrict__ bias,
                              unsigned short* __restrict__ r0) {
    int bm = blockIdx.x;
    int b = bm / MRED, m = bm % MRED;
    int i = m / 7, j = m % 7;
    int r00 = b * NTOK + (2 * i) * 14 + 2 * j;
    for (int c = threadIdx.x; c < CDIM; c += 256) {
        float acc = bias[c];
        acc += bf2f(y[(size_t)(r00)      * CDIM + c]) * w[c * 4 + 0];
        acc += bf2f(y[(size_t)(r00 + 1)  * CDIM + c]) * w[c * 4 + 1];
        acc += bf2f(y[(size_t)(r00 + 14) * CDIM + c]) * w[c * 4 + 2];
        acc += bf2f(y[(size_t)(r00 + 15) * CDIM + c]) * w[c * 4 + 3];
        r0[(size_t)bm * CDIM + c] = f2bf(acc);
    }
}

// ---------------------------------------------------------------------------
// MFMA GEMM: 128x192 tile, BK=64, 8 waves (2M x 4N), per-wave 64x48 output
// (acc[4][3] = 48 AGPR; ~50 VGPR -> 4 waves/SIMD, 2 blocks/CU).
// Ring-2 LDS: slot = A 16KB + B 24KB = 40KB; 2 slots = 80KB (= the full
// per-block budget at 2 blocks/CU). 24 MFMA per iter vs 16 at BN=128, same
// fixed per-iter cost (barriers/drain/5 gllds) -> higher MFMA fraction.
// All N in this net divide 192 exactly (768/960/1728/3072) -> zero pad work.
// LDS rows are 128B (8 chunks): XOR swizzle chunk ^= (row&7); gllds writes
// linearly so the GLOBAL source chunk is inverse-swizzled (involution) and
// ds_read applies the same XOR (rule #21). 48&7==0 and 16&7==0 keep the
// fragment-row swizzle uniform: row&7 == l16&7 for every frag.
// MODE 0: bf16 = acc ; 1: fp32 = acc+bias ; 2: fp32 += acc+bias ;
// 3: bf16 = gelu(acc+bias).  Epilogue masks gr<M, gc<N.
// ---------------------------------------------------------------------------
template <int MODE>
__global__ __launch_bounds__(512, 4) void gemm192_kernel(
    const unsigned short* __restrict__ A,
    const unsigned short* __restrict__ Bt,
    const float* __restrict__ bias,
    float* __restrict__ outF,
    unsigned short* __restrict__ outB,
    int M, int N, int K, int NR, int NC) {
    extern __shared__ __align__(16) char sb[];   // 2 slots x 40KB

    // XCD-aware tile swizzle: groups of 8 row-tiles x NC col-tiles
    int id = blockIdx.x;
    int gsize = 8 * NC;
    int g = id / gsize;
    int local = id - g * gsize;
    int rbase = g * 8;
    int Gg = NR - rbase; if (Gg > 8) Gg = 8;
    int col = local / Gg;
    int row = rbase + (local - col * Gg);
    int m0 = row * 128, n0 = col * 192;

    int tid = threadIdx.x;
    int w = tid >> 6, lane = tid & 63, quad = lane >> 4, l16 = lane & 15;
    int wm = w >> 2, wn = w & 3;        // 2 x 4 wave grid

    // ---- staging sources: thread t -> row r=t>>3 (+64/+128), phys chunk
    //      p=t&7; logical source chunk qc = p ^ (r&7) (inverse swizzle;
    //      (r+64)&7 == (r+128)&7 == r&7 so one qc serves all loads) ----
    int r = tid >> 3;
    int qc = (tid & 7) ^ (r & 7);
    const unsigned short* aS0 = A  + (size_t)(m0 + r) * K + qc * 8;
    const unsigned short* aS1 = A  + (size_t)(m0 + r + 64) * K + qc * 8;
    const unsigned short* bS0 = Bt + (size_t)(n0 + r) * K + qc * 8;
    const unsigned short* bS1 = Bt + (size_t)(n0 + r + 64) * K + qc * 8;
    const unsigned short* bS2 = Bt + (size_t)(n0 + r + 128) * K + qc * 8;

    // ---- read-side fragment byte offsets (swizzled) ----
    int s7 = l16 & 7;
    int sq0 = ((0 + quad) ^ s7) * 16;
    int sq1 = ((4 + quad) ^ s7) * 16;
    int aBase = (wm * 64 + l16) * 128;            // + mi*2048 + slot
    int bBase = 16384 + (wn * 48 + l16) * 128;    // + ni*2048 + slot

    f32x4 zero4 = {0.f, 0.f, 0.f, 0.f};
    f32x4 acc[4][3];
#pragma unroll
    for (int mi = 0; mi < 4; mi++)
#pragma unroll
        for (int ni = 0; ni < 3; ni++) acc[mi][ni] = zero4;

    int NT = K >> 6;

#define STAGE192(slotptr, tt)                                    \
    do {                                                         \
        int ko_ = (tt) * 64;                                     \
        GLLDS16(aS0 + ko_, (slotptr) + w * 1024);                \
        GLLDS16(aS1 + ko_, (slotptr) + 8192  + w * 1024);        \
        GLLDS16(bS0 + ko_, (slotptr) + 16384 + w * 1024);        \
        GLLDS16(bS1 + ko_, (slotptr) + 24576 + w * 1024);        \
        GLLDS16(bS2 + ko_, (slotptr) + 32768 + w * 1024);        \
    } while (0)

    // prologue: stage tile 0
    STAGE192(sb, 0);
    asm volatile("s_waitcnt vmcnt(0)" ::: "memory");
    __builtin_amdgcn_s_barrier();

    for (int t = 0; t < NT; ++t) {
        char* sc = sb + (size_t)(t & 1) * 40960;
        if (t + 1 < NT) {
            char* sp = sb + (size_t)((t + 1) & 1) * 40960;
            STAGE192(sp, t + 1);
        }
        bf16x8 af[4], bfr[3];
        // ---- kk = 0 ----
#pragma unroll
        for (int mi = 0; mi < 4; mi++)
            af[mi] = *(const bf16x8*)(sc + aBase + mi * 2048 + sq0);
#pragma unroll
        for (int ni = 0; ni < 3; ni++)
            bfr[ni] = *(const bf16x8*)(sc + bBase + ni * 2048 + sq0);
        __builtin_amdgcn_s_setprio(1);
#pragma unroll
        for (int mi = 0; mi < 4; mi++)
#pragma unroll
            for (int ni = 0; ni < 3; ni++)
                acc[mi][ni] = __builtin_amdgcn_mfma_f32_16x16x32_bf16(
                    af[mi], bfr[ni], acc[mi][ni], 0, 0, 0);
        __builtin_amdgcn_s_setprio(0);
        // ---- kk = 1 ----
#pragma unroll
        for (int mi = 0; mi < 4; mi++)
            af[mi] = *(const bf16x8*)(sc + aBase + mi * 2048 + sq1);
#pragma unroll
        for (int ni = 0; ni < 3; ni++)
            bfr[ni] = *(const bf16x8*)(sc + bBase + ni * 2048 + sq1);
        __builtin_amdgcn_s_setprio(1);
#pragma unroll
        for (int mi = 0; mi < 4; mi++)
#pragma unroll
            for (int ni = 0; ni < 3; ni++)
                acc[mi][ni] = __builtin_amdgcn_mfma_f32_16x16x32_bf16(
                    af[mi], bfr[ni], acc[mi][ni], 0, 0, 0);
        __builtin_amdgcn_s_setprio(0);
        asm volatile("s_waitcnt vmcnt(0)" ::: "memory");
        __builtin_amdgcn_s_barrier();
    }
#undef STAGE192

    // --- epilogue: repack each wave's 16x48 slices through private LDS ---
    __syncthreads();
    float* eld = (float*)(sb + w * 3072);
    int colbase = n0 + wn * 48;
#pragma unroll
    for (int mi = 0; mi < 4; mi++) {
#pragma unroll
        for (int ni = 0; ni < 3; ni++)
#pragma unroll
            for (int rr = 0; rr < 4; rr++)
                eld[(quad * 4 + rr) * 48 + ni * 16 + l16] = acc[mi][ni][rr];
        int rowb = m0 + wm * 64 + mi * 16;
#pragma unroll
        for (int p = 0; p < 3; p++) {
            int idx = p * 64 + lane;       // 0..191
            int r2 = idx / 12;             // 0..15
            int cg = idx - r2 * 12;        // 0..11
            int c2 = cg * 4;
            int gr = rowb + r2, gc = colbase + c2;
            if (gr < M && gc < N) {
                f32x4 v4 = *(f32x4*)(eld + r2 * 48 + c2);
                if (MODE == 0) {
                    u16x4 h;
#pragma unroll
                    for (int e = 0; e < 4; e++) h[e] = f2bf(v4[e]);
                    *(u16x4*)(outB + (size_t)gr * N + gc) = h;
                } else {
                    f32x4 b4 = *(const f32x4*)(bias + gc);
                    if (MODE == 1) {
                        *(f32x4*)(outF + (size_t)gr * N + gc) = v4 + b4;
                    } else if (MODE == 2) {
                        f32x4 o4 = *(f32x4*)(outF + (size_t)gr * N + gc);
                        *(f32x4*)(outF + (size_t)gr * N + gc) = o4 + v4 + b4;
                    } else {  // MODE 3
                        u16x4 h;
#pragma unroll
                        for (int e = 0; e < 4; e++) h[e] = f2bf(gelu_f(v4[e] + b4[e]));
                        *(u16x4*)(outB + (size_t)gr * N + gc) = h;
                    }
                }
            }
        }
    }
}

// ---------------------------------------------------------------------------
// MFMA attention. One block per (b,h), 8 waves. Swapped-operand QK^T:
// S^T = mfma(A=K_frag, B=Q_frag) so the k-reduction is in-lane + 2 shfl_xor.
// V staged in LDS pre-permuted to the PV B-operand k-order, so the C-layout
// P^T fragments feed PV mfma directly (no cross-lane shuffles):
//   V2[d][c], c = 32s + 8q + j  ->  ktilde = 32s + 16*(j>=4) + 4q + (j&3)
// K_lds[64][96] (d-pad zeroed); O^T bounced via per-wave LDS tile (stride 72)
// to coalesced 16B stores. k>=49 masked at softmax; V2 pad rows zero.
// ---------------------------------------------------------------------------
__global__ __launch_bounds__(512, 4) void attn_kernel(
    const unsigned short* __restrict__ qb,   // (ROWS, CNDIM)
    const unsigned short* __restrict__ kv,   // (RROWS, KVN)
    unsigned short* __restrict__ ob) {       // (ROWS, CDIM)
    __shared__ __align__(16) unsigned short Ks[64 * 96];    // 12288 B
    __shared__ __align__(16) unsigned short V2[64 * 136];   // 17408 B (136 pad, cols 0..127 used)
    __shared__ __align__(16) unsigned short Os[8 * 16 * 72]; // 18432 B per-wave bounce

    int bh = blockIdx.x;
    int b = bh / NHEAD, h = bh % NHEAD;
    int tid = threadIdx.x;

    // --- zero K d-pad (cols 80..95, rows 0..48); disjoint from staged region ---
    for (int idx = tid; idx < 49 * 8; idx += 512) {
        int m = idx >> 3, c = idx & 7;
        ((unsigned int*)Ks)[m * 48 + 40 + c] = 0u;
    }
    // --- stage K rows: K_lds[m][d] = kv[b*49+m][h*80+d], 16B chunks ---
    for (int idx = tid; idx < 49 * 10; idx += 512) {
        int m = idx / 10, c = idx % 10;
        bf16x8 v = *(const bf16x8*)(kv + (size_t)(b * MRED + m) * KVN + h * HDK + c * 8);
        *(bf16x8*)(Ks + m * 96 + c * 8) = v;
    }
    // --- stage V pre-permuted: V2[d][c] = V[ktilde(c)][d] or 0 ---
    for (int idx = tid; idx < 64 * 128; idx += 512) {
        int d = idx >> 7, c = idx & 127;
        int s = c >> 5, q = (c >> 3) & 3, j = c & 7;
        int kt = s * 32 + ((j >> 2) << 4) + q * 4 + (j & 3);
        unsigned short val = 0;
        if (kt < MRED) val = kv[(size_t)(b * MRED + kt) * KVN + 960 + h * HD + d];
        V2[d * 136 + c] = val;
    }
    __syncthreads();

    int wv = tid >> 6, lane = tid & 63, quad = lane >> 4, l16 = lane & 15;
    unsigned short* Ow = Os + wv * 16 * 72;
    const float scale = 0.11180339887498949f;  // 1/sqrt(80)
    f32x4 zero4 = {0.f, 0.f, 0.f, 0.f};

#pragma unroll
    for (int gi = 0; gi < 2; ++gi) {
        int qg = wv + gi * 8;
        if (qg >= 13) break;
        // Q B-fragments (global, L2/L3-resident): B[d][q], d = quad*8+j
        const unsigned short* qrow =
            qb + (size_t)(b * NTOK + qg * 16 + l16) * CNDIM + h * HDK + quad * 8;
        bf16x8 bq0 = *(const bf16x8*)(qrow);
        bf16x8 bq1 = *(const bf16x8*)(qrow + 32);
        bf16x8 bq2 = *(const bf16x8*)(qrow + 64);

        // S^T = K @ Q^T : 4 k-frags x 3 K32-steps
        f32x4 sf[4];
#pragma unroll
        for (int kf = 0; kf < 4; kf++) sf[kf] = zero4;
#pragma unroll
        for (int kf = 0; kf < 4; kf++) {
            const unsigned short* kr = Ks + (kf * 16 + l16) * 96 + quad * 8;
            sf[kf] = __builtin_amdgcn_mfma_f32_16x16x32_bf16(
                *(const bf16x8*)(kr), bq0, sf[kf], 0, 0, 0);
            sf[kf] = __builtin_amdgcn_mfma_f32_16x16x32_bf16(
                *(const bf16x8*)(kr + 32), bq1, sf[kf], 0, 0, 0);
            sf[kf] = __builtin_amdgcn_mfma_f32_16x16x32_bf16(
                *(const bf16x8*)(kr + 64), bq2, sf[kf], 0, 0, 0);
        }

        // softmax over k (rows of S^T): lane holds k = 16kf + 4quad + r, col q=l16
        float p[4][4];
        float mx = -1e30f;
#pragma unroll
        for (int kf = 0; kf < 4; kf++)
#pragma unroll
            for (int r = 0; r < 4; r++) {
                float v = sf[kf][r] * scale;
                if (kf == 3) {
                    // k = 48 + 4*quad + r valid only for quad==0 && r==0
                    v = (r == 0 && quad == 0) ? v : -1e30f;
                }
                p[kf][r] = v;
                mx = fmaxf(mx, v);
            }
        mx = fmaxf(mx, __shfl_xor(mx, 16));
        mx = fmaxf(mx, __shfl_xor(mx, 32));
        float sum = 0.f;
#pragma unroll
        for (int kf = 0; kf < 4; kf++)
#pragma unroll
            for (int r = 0; r < 4; r++) {
                float e = __expf(p[kf][r] - mx);
                p[kf][r] = e;
                sum += e;
            }
        sum += __shfl_xor(sum, 16);
        sum += __shfl_xor(sum, 32);
        float inv = 1.0f / sum;
#pragma unroll
        for (int kf = 0; kf < 4; kf++)
#pragma unroll
            for (int r = 0; r < 4; r++) p[kf][r] *= inv;

        // pack P^T to bf16 pairs (r0,r1),(r2,r3) per frag
        unsigned int W[4][2];
#pragma unroll
        for (int kf = 0; kf < 4; kf++) {
            W[kf][0] = pack2bf(p[kf][0], p[kf][1]);
            W[kf][1] = pack2bf(p[kf][2], p[kf][3]);
        }

        // PV: O^T = V2 @ P : 4 d-frags x 2 K32-steps (V2 pre-permuted)
        f32x4 oacc[4];
#pragma unroll
        for (int df = 0; df < 4; df++) oacc[df] = zero4;
#pragma unroll
        for (int s = 0; s < 2; s++) {
            union { unsigned int u[4]; bf16x8 v; } bb;
            bb.u[0] = W[2 * s][0];
            bb.u[1] = W[2 * s][1];
            bb.u[2] = W[2 * s + 1][0];
            bb.u[3] = W[2 * s + 1][1];
#pragma unroll
            for (int df = 0; df < 4; df++) {
                const unsigned short* vr = V2 + (df * 16 + l16) * 136 + s * 32 + quad * 8;
                oacc[df] = __builtin_amdgcn_mfma_f32_16x16x32_bf16(
                    *(const bf16x8*)(vr), bb.v, oacc[df], 0, 0, 0);
            }
        }

        // O^T frags (row d = 16df+4quad+r, col q = l16) -> per-wave LDS bounce
#pragma unroll
        for (int df = 0; df < 4; df++) {
#pragma unroll
            for (int wp = 0; wp < 2; wp++) {
                unsigned int pk = pack2bf(oacc[df][2 * wp], oacc[df][2 * wp + 1]);
                *(unsigned int*)(Ow + l16 * 72 + df * 16 + quad * 4 + 2 * wp) = pk;
            }
        }
        // readback (same wave; compiler inserts lgkm wait) -> coalesced stores
        int q = lane >> 2, cch = lane & 3;
        int grow = qg * 16 + q;
        if (grow < NTOK) {
            unsigned short* dst = ob + (size_t)(b * NTOK + grow) * CDIM + h * HD + cch * 8;
            bf16x8 v0 = *(const bf16x8*)(Ow + q * 72 + cch * 8);
            bf16x8 v1 = *(const bf16x8*)(Ow + q * 72 + cch * 8 + 32);
            *(bf16x8*)(dst) = v0;
            *(bf16x8*)(dst + 32) = v1;
        }
    }
}

// ---------------------------------------------------------------------------

extern "C" void kernel_launch(void* const* d_in, const int* in_sizes, int n_in,
                              void* d_out, int out_size, void* d_ws, size_t ws_size,
                              hipStream_t stream) {
    (void)in_sizes; (void)n_in; (void)out_size; (void)ws_size;
    const float* x_in   = (const float*)d_in[0];
    const float* q_w    = (const float*)d_in[1];
    const float* dw_w   = (const float*)d_in[2];
    const float* dw_b   = (const float*)d_in[3];
    const float* pw_w   = (const float*)d_in[4];
    const float* pw_b   = (const float*)d_in[5];
    const float* lnr_g  = (const float*)d_in[6];
    const float* lnr_b  = (const float*)d_in[7];
    const float* k_w    = (const float*)d_in[8];
    const float* v_w    = (const float*)d_in[9];
    const float* proj_w = (const float*)d_in[10];
    const float* proj_b = (const float*)d_in[11];
    const float* ln1_g  = (const float*)d_in[12];
    const float* ln1_b  = (const float*)d_in[13];
    const float* ln2_g  = (const float*)d_in[14];
    const float* ln2_b  = (const float*)d_in[15];
    const float* fc1_w  = (const float*)d_in[16];
    const float* fc1_b  = (const float*)d_in[17];
    const float* fc2_w  = (const float*)d_in[18];
    const float* fc2_b  = (const float*)d_in[19];
    float* xout = (float*)d_out;
    char* ws = (char*)d_ws;

    // dynamic-LDS opt-in (80KB ring-2)
    static bool attr_done = false;
    if (!attr_done) {
        hipFuncSetAttribute(reinterpret_cast<const void*>(&gemm192_kernel<0>),
                            hipFuncAttributeMaxDynamicSharedMemorySize, 81920);
        hipFuncSetAttribute(reinterpret_cast<const void*>(&gemm192_kernel<1>),
                            hipFuncAttributeMaxDynamicSharedMemorySize, 81920);
        hipFuncSetAttribute(reinterpret_cast<const void*>(&gemm192_kernel<2>),
                            hipFuncAttributeMaxDynamicSharedMemorySize, 81920);
        hipFuncSetAttribute(reinterpret_cast<const void*>(&gemm192_kernel<3>),
                            hipFuncAttributeMaxDynamicSharedMemorySize, 81920);
        attr_done = true;
    }

    // ---- workspace layout (bf16 elems; weight rows padded: 960->1024,
    //      1728->1792; activation M padded to 3328 rows where needed) ----
    const size_t PL = 8601600;
    const size_t offQ = 0, offPW = 786432, offKV = 1572864,
                 offPJ = 3293184, offF1 = 3883008, offF2 = 6242304;
    unsigned short* W = (unsigned short*)ws;
    char* act = ws + PL * 2 * L_LAYERS;                 // 68,812,800 B weights
    unsigned short* y_bf = (unsigned short*)act;        // 12544*768 bf16
    char* blk = act + (size_t)ROWS * CDIM * 2;
    unsigned short* q_bf  = (unsigned short*)(blk);                 // 12544*960
    unsigned short* r0_bf = (unsigned short*)(blk + 24084480);      // 3328*768 (pad rows)
    float*          pw_f  = (float*)        (blk + 29196288);       // 3136*960 f32
    unsigned short* r_bf  = (unsigned short*)(blk + 41238528);      // 3328*960 (pad rows)
    unsigned short* kv_bf = (unsigned short*)(blk + 47628288);      // 3136*1728
    unsigned short* o_bf  = (unsigned short*)(blk + 58466304);      // 12544*768
    unsigned short* h_bf  = (unsigned short*)(blk);                 // 12544*3072 (aliases, dead by then)
    unsigned short* z_bf  = y_bf;

    hipMemcpyAsync(xout, x_in, (size_t)ROWS * CDIM * sizeof(float),
                   hipMemcpyDeviceToDevice, stream);

    // ---- weight prep (fp32 KxN -> bf16 NxK), all layers via grid.z ----
    dim3 tb(32, 8);
    transpose_bf16_kernel<<<dim3(CNDIM / 32, CDIM / 32, L_LAYERS), tb, 0, stream>>>(
        q_w, W + offQ, CDIM, CNDIM, (size_t)CDIM * CNDIM, PL);
    transpose_bf16_kernel<<<dim3(CNDIM / 32, CDIM / 32, L_LAYERS), tb, 0, stream>>>(
        pw_w, W + offPW, CDIM, CNDIM, (size_t)CDIM * CNDIM, PL);
    transpose_bf16_kernel<<<dim3(CNDIM / 32, CNDIM / 32, L_LAYERS), tb, 0, stream>>>(
        k_w, W + offKV, CNDIM, CNDIM, (size_t)CNDIM * CNDIM, PL);
    transpose_bf16_kernel<<<dim3(CDIM / 32, CNDIM / 32, L_LAYERS), tb, 0, stream>>>(
        v_w, W + offKV + (size_t)CNDIM * CNDIM, CNDIM, CDIM, (size_t)CNDIM * CDIM, PL);
    transpose_bf16_kernel<<<dim3(CDIM / 32, CDIM / 32, L_LAYERS), tb, 0, stream>>>(
        proj_w, W + offPJ, CDIM, CDIM, (size_t)CDIM * CDIM, PL);
    transpose_bf16_kernel<<<dim3(HIDDIM / 32, CDIM / 32, L_LAYERS), tb, 0, stream>>>(
        fc1_w, W + offF1, CDIM, HIDDIM, (size_t)CDIM * HIDDIM, PL);
    transpose_bf16_kernel<<<dim3(CDIM / 32, HIDDIM / 32, L_LAYERS), tb, 0, stream>>>(
        fc2_w, W + offF2, HIDDIM, CDIM, (size_t)HIDDIM * CDIM, PL);

    for (int l = 0; l < L_LAYERS; l++) {
        const unsigned short* wl = W + (size_t)l * PL;
        // LN1 -> y (single-pass C=768)
        ln768_kernel<<<ROWS / 4, 256, 0, stream>>>(xout, ln1_g + l * CDIM, ln1_b + l * CDIM,
                                                   y_bf, ROWS, 1e-6f);
        // q = y @ q_w  (12544 x 960 x 768), tiles 98 x 5 (exact)
        gemm192_kernel<0><<<98 * 5, 512, 81920, stream>>>(
            y_bf, wl + offQ, nullptr, nullptr, q_bf, ROWS, CNDIM, CDIM, 98, 5);
        // depthwise conv reduce -> r0 (3136 x 768)
        dwconv_kernel<<<RROWS, 256, 0, stream>>>(y_bf, dw_w + (size_t)l * CDIM * 4,
                                                 dw_b + l * CDIM, r0_bf);
        // pw: r0 @ pw_w + b  (3136 x 960 x 768) -> fp32, tiles 25 x 5
        gemm192_kernel<1><<<25 * 5, 512, 81920, stream>>>(
            r0_bf, wl + offPW, pw_b + l * CNDIM, pw_f, nullptr, RROWS, CNDIM, CDIM, 25, 5);
        // norm_act: LN(eps 1e-5) + GELU -> r (generic C=960)
        ln_kernel<<<RROWS / 4, 256, 0, stream>>>(pw_f, lnr_g + l * CNDIM, lnr_b + l * CNDIM,
                                                 r_bf, RROWS, CNDIM, 1e-5f, 1);
        // fused kv = r @ [k_w | v_w]  (3136 x 1728 x 960), tiles 25 x 9 (exact)
        gemm192_kernel<0><<<25 * 9, 512, 81920, stream>>>(
            r_bf, wl + offKV, nullptr, nullptr, kv_bf, RROWS, KVN, CNDIM, 25, 9);
        // attention -> o (bf16), MFMA flash-style
        attn_kernel<<<BSZ * NHEAD, 512, 0, stream>>>(q_bf, kv_bf, o_bf);
        // x += o @ proj_w + proj_b  (12544 x 768 x 768), tiles 98 x 4
        gemm192_kernel<2><<<98 * 4, 512, 81920, stream>>>(
            o_bf, wl + offPJ, proj_b + l * CDIM, xout, nullptr, ROWS, CDIM, CDIM, 98, 4);
        // LN2 -> z (single-pass C=768)
        ln768_kernel<<<ROWS / 4, 256, 0, stream>>>(xout, ln2_g + l * CDIM, ln2_b + l * CDIM,
                                                   z_bf, ROWS, 1e-6f);
        // h = gelu(z @ fc1 + b)  (12544 x 3072 x 768), tiles 98 x 16
        gemm192_kernel<3><<<98 * 16, 512, 81920, stream>>>(
            z_bf, wl + offF1, fc1_b + l * HIDDIM, nullptr, h_bf, ROWS, HIDDIM, CDIM, 98, 16);
        // x += h @ fc2 + b  (12544 x 768 x 3072), tiles 98 x 4
        gemm192_kernel<2><<<98 * 4, 512, 81920, stream>>>(
            h_bf, wl + offF2, fc2_b + l * CDIM, xout, nullptr, ROWS, CDIM, HIDDIM, 98, 4);
    }
}